// Round 3
// baseline (368.567 us; speedup 1.0000x reference)
//
#include <hip/hip_runtime.h>

// VQ nearest-codebook: MFMA bf16 hi/lo filter + exact fp32-emulated rescore.
// R9: block-shared B-frags, double-buffered LDS + global_load_lds(16B);
//     packed-uint top-2 epilogue; A = -(2x), MFMA C-init = se+1.5.
// R10: v_med3_u32 2nd-best update; v_cvt_pk_bf16_f32 A-prep.
// R11 (this round): occupancy was launch-capped at 16 waves/CU (grid 1024 x
//     4-wave blocks = 4 blocks/CU, 50% max; measured 33%, 33% issue-idle).
//     Split-K in-block: 512-thread blocks (8 waves), waves h=0/1 scan codebook
//     halves (16 chunks each) for the same 128 rows; exact top-2 merge in LDS:
//     p1=min(a1,b1), p2=min(max(a1,b1),min(a2,b2)). tc-outer MFMA/epilogue
//     to halve bfr/acc live-sets (fit 64 VGPR for 8 waves/SIMD).
//
// ref semantics (verified R2/R3/R6/R8): d[n,k] = fl(fl(sx+se) - chain),
// sx/se = numpy pairwise-8 tree of squares, chain = sequential FMA over d of
// (2x)*e, argmin first-index tie-break. Ambiguous rows (gap <= ~3.05e-5) get
// the exact fp32-emulated rescore.

#define D 64
#define K 1024
#define HW 4096
#define NTOTAL 131072

// workspace layout (bytes)
#define BF_OFF   0          // B-frags: 32 chunks * 8 frags * 64 lanes * 16B = 256 KB
#define SE_OFF   262144     // 4 KB
#define CNT_OFF  266240
#define LIST_OFF 266244
#define LIST_CAP 65536
#define WS_NEED  (266244 + LIST_CAP * 4)

// packed-gap margin: 2^17 packed units = 2^-15 = 3.05e-5 value gap.
#define MARGIN_P 131072u

typedef __attribute__((ext_vector_type(8))) short bf16x8;   // 8 bf16 = 4 VGPR
typedef __attribute__((ext_vector_type(4))) float f32x4;
typedef __attribute__((ext_vector_type(4))) unsigned int u32x4;

__device__ __forceinline__ unsigned short bf16_rne(float f) {
    unsigned u = __float_as_uint(f);
    u += 0x7fffu + ((u >> 16) & 1u);
    return (unsigned short)(u >> 16);
}
__device__ __forceinline__ float bf16_to_f(unsigned short h) {
    return __uint_as_float(((unsigned)h) << 16);
}

// HW packed f32->bf16 RNE convert: low16 = bf16(a), high16 = bf16(b).
__device__ __forceinline__ unsigned cvt_pk_bf16(float a, float b) {
    unsigned r;
    asm("v_cvt_pk_bf16_f32 %0, %1, %2" : "=v"(r) : "v"(a), "v"(b));
    return r;
}

// numpy pairwise sum, n=64
__device__ __forceinline__ float np_sumsq64(const float* v) {
    float r[8];
#pragma unroll
    for (int j = 0; j < 8; ++j) r[j] = __fmul_rn(v[j], v[j]);
#pragma unroll
    for (int i = 8; i < 64; i += 8)
#pragma unroll
        for (int j = 0; j < 8; ++j)
            r[j] = __fadd_rn(r[j], __fmul_rn(v[i + j], v[i + j]));
    float s01 = __fadd_rn(r[0], r[1]), s23 = __fadd_rn(r[2], r[3]);
    float s45 = __fadd_rn(r[4], r[5]), s67 = __fadd_rn(r[6], r[7]);
    return __fadd_rn(__fadd_rn(s01, s23), __fadd_rn(s45, s67));
}

// --- prep: codebook -> se + B-frags in lane order; also zeroes CNT ---
__global__ __launch_bounds__(256) void prep_cb(const float* __restrict__ cb,
                                               char* __restrict__ ws) {
    if (blockIdx.x == 0 && threadIdx.x == 0) *(int*)(ws + CNT_OFF) = 0;
    int k = blockIdx.x * 256 + threadIdx.x;          // grid 4*256 = 1024
    const float* e = cb + k * D;
    float v[D];
#pragma unroll
    for (int d = 0; d < D; ++d) v[d] = e[d];
    ((float*)(ws + SE_OFF))[k] = np_sumsq64(v);
    unsigned short hh[D], ll[D];
#pragma unroll
    for (int d = 0; d < D; ++d) {
        hh[d] = bf16_rne(v[d]);
        ll[d] = bf16_rne(v[d] - bf16_to_f(hh[d]));
    }
    const int c = k >> 5, tc = (k >> 4) & 1, c16 = k & 15;
    uint4* bf = (uint4*)(ws + BF_OFF);
#pragma unroll
    for (int qd = 0; qd < 8; ++qd) {                 // d0 = qd*8
        int q = qd & 3, jh = qd >> 2;                // d0 = q*8 + 32*jh
        int l = q * 16 + c16;
        uint4 a, b;
        const unsigned short* h = hh + qd * 8;
        const unsigned short* lo = ll + qd * 8;
        a.x = h[0] | (h[1] << 16);  a.y = h[2] | (h[3] << 16);
        a.z = h[4] | (h[5] << 16);  a.w = h[6] | (h[7] << 16);
        b.x = lo[0] | (lo[1] << 16); b.y = lo[2] | (lo[3] << 16);
        b.z = lo[4] | (lo[5] << 16); b.w = lo[6] | (lo[7] << 16);
        bf[(c * 8 + tc * 4 + jh) * 64 + l]       = a;   // hi -> j=jh
        bf[(c * 8 + tc * 4 + 2 + jh) * 64 + l]   = b;   // lo -> j=2+jh
    }
}

// --- main: 512 threads = 8 waves; wave (h, wh): h = codebook half, wh = row group ---
__global__ __launch_bounds__(512, 8) void vq_main(const float* __restrict__ in,
                                                  const float* __restrict__ cb,
                                                  float* __restrict__ out,
                                                  char* __restrict__ ws) {
    __shared__ uint4 s_bf[2][2][8][64];   // [half][dbuf][frag][lane] = 32 KB
    __shared__ unsigned s_p1[2][128], s_p2[2][128];
    __shared__ int s_widx[128];

    const int t = threadIdx.x;
    const int nb = blockIdx.x * 128;          // grid 1024
    const int b = nb >> 12, hw0 = nb & (HW - 1);
    const int lane = t & 63, q = lane >> 4, c16 = lane & 15;
    const int w = t >> 6, wh = w & 3, h = w >> 2;

    // ---- A-frags direct from global. A = -(2x), hi/lo split via HW cvt_pk.
    // A[m=c16][k=q*8+i], d = 32*jh + q*8 + i. Rows: wh*32 + tv*16 + c16.
    bf16x8 af[2][4];
#pragma unroll
    for (int tv = 0; tv < 2; ++tv) {
        const float* xp = in + (size_t)b * (D * HW) + hw0 + wh * 32 + tv * 16 + c16;
#pragma unroll
        for (int jh = 0; jh < 2; ++jh) {
            float ny[8];
#pragma unroll
            for (int i = 0; i < 8; ++i)
                ny[i] = __fmul_rn(xp[(size_t)(jh * 32 + q * 8 + i) * HW], -2.0f);
            u32x4 hv, lv;
#pragma unroll
            for (int p = 0; p < 4; ++p) {
                unsigned hp = cvt_pk_bf16(ny[2 * p], ny[2 * p + 1]);
                float h0 = __uint_as_float(hp << 16);
                float h1 = __uint_as_float(hp & 0xFFFF0000u);
                unsigned lp = cvt_pk_bf16(__fsub_rn(ny[2 * p], h0),
                                          __fsub_rn(ny[2 * p + 1], h1));
                hv[p] = hp; lv[p] = lp;
            }
            af[tv][jh]     = __builtin_bit_cast(bf16x8, hv);   // j=0,1: hi
            af[tv][2 + jh] = __builtin_bit_cast(bf16x8, lv);   // j=2,3: lo
        }
    }

    const float* seg = (const float*)(ws + SE_OFF);
    const char* bfbase = ws + BF_OFF;

    unsigned p1[8], p2[8];
#pragma unroll
    for (int s = 0; s < 8; ++s) { p1[s] = 0xFFFFFFFFu; p2[s] = 0xFFFFFFFFu; }

    // stage chunk h*16 into buf 0 (wave stages frags 2wh, 2wh+1 of its stream)
    {
        const char* g = bfbase + ((size_t)((h * 16) * 8 + 2 * wh) * 64 + lane) * 16;
        __builtin_amdgcn_global_load_lds((const __attribute__((address_space(1))) void*)g,
            (__attribute__((address_space(3))) void*)&s_bf[h][0][2 * wh][0], 16, 0, 0);
        __builtin_amdgcn_global_load_lds((const __attribute__((address_space(1))) void*)(g + 1024),
            (__attribute__((address_space(3))) void*)&s_bf[h][0][2 * wh + 1][0], 16, 0, 0);
    }
    __syncthreads();

    for (int i = 0; i < 16; ++i) {
        const int cur = i & 1;
        const int ch = h * 16 + i;                   // this wave's chunk
        if (i + 1 < 16) {   // prefetch next chunk of this stream (async)
            const char* g = bfbase + ((size_t)((ch + 1) * 8 + 2 * wh) * 64 + lane) * 16;
            __builtin_amdgcn_global_load_lds((const __attribute__((address_space(1))) void*)g,
                (__attribute__((address_space(3))) void*)&s_bf[h][cur ^ 1][2 * wh][0], 16, 0, 0);
            __builtin_amdgcn_global_load_lds((const __attribute__((address_space(1))) void*)(g + 1024),
                (__attribute__((address_space(3))) void*)&s_bf[h][cur ^ 1][2 * wh + 1][0], 16, 0, 0);
        }

        // tc-outer: halves bfr/acc live-sets (fits 8 waves/SIMD reg budget)
#pragma unroll
        for (int tc = 0; tc < 2; ++tc) {
            float sec = __fadd_rn(seg[ch * 32 + tc * 16 + c16], 1.5f);

            bf16x8 bfr[4];
#pragma unroll
            for (int j = 0; j < 4; ++j)
                bfr[j] = *(const bf16x8*)&s_bf[h][cur][tc * 4 + j][lane];

            f32x4 acc[2];
#pragma unroll
            for (int tv = 0; tv < 2; ++tv)
                acc[tv] = (f32x4){sec, sec, sec, sec};

            // K=192: (-yh)*eh (2) + (-yl)*eh (2) + (-yh)*el (2) on se'
            const int sa[6] = {0, 1, 2, 3, 0, 1};
            const int sb[6] = {0, 1, 0, 1, 2, 3};
#pragma unroll
            for (int s = 0; s < 6; ++s)
#pragma unroll
                for (int tv = 0; tv < 2; ++tv)
                    acc[tv] = __builtin_amdgcn_mfma_f32_16x16x32_bf16(
                        af[tv][sa[s]], bfr[sb[s]], acc[tv], 0, 0, 0);

            // epilogue: p = ((bits>>1)<<10) | code; p2'=med3(p,p1,p2), p1'=min
            unsigned code = (unsigned)(ch * 32 + tc * 16 + c16);
#pragma unroll
            for (int tv = 0; tv < 2; ++tv)
#pragma unroll
                for (int r = 0; r < 4; ++r) {
                    unsigned u = __float_as_uint(acc[tv][r]);
                    unsigned p = ((u >> 1) << 10) | code;
                    int s = tv * 4 + r;
                    unsigned m;
                    asm("v_med3_u32 %0, %1, %2, %3"
                        : "=v"(m) : "v"(p), "v"(p1[s]), "v"(p2[s]));
                    p2[s] = m;
                    p1[s] = p < p1[s] ? p : p1[s];
                }
        }
        __syncthreads();   // all waves done with buf cur; prefetch drained
    }

    // ---- cross-lane top-2 merge over the 16 col-lanes (bits 0-3 of lane)
#pragma unroll
    for (int m = 1; m < 16; m <<= 1)
#pragma unroll
        for (int s = 0; s < 8; ++s) {
            unsigned o1 = (unsigned)__shfl_xor((int)p1[s], m, 64);
            unsigned o2 = (unsigned)__shfl_xor((int)p2[s], m, 64);
            unsigned lo = p1[s] < o1 ? p1[s] : o1;
            unsigned hi = p1[s] < o1 ? o1 : p1[s];
            unsigned n2 = p2[s] < o2 ? p2[s] : o2;
            p2[s] = hi < n2 ? hi : n2;
            p1[s] = lo;
        }

    // per-half results -> LDS
    if (c16 == 0) {
#pragma unroll
        for (int s = 0; s < 8; ++s) {
            int tv = s >> 2, r = s & 3;
            int row = wh * 32 + tv * 16 + q * 4 + r;    // block-local
            s_p1[h][row] = p1[s];
            s_p2[h][row] = p2[s];
        }
    }
    __syncthreads();

    // ---- merge halves (exact top-2 of two sorted pairs), flag + widx
    if (t < 128) {
        unsigned a1 = s_p1[0][t], b1 = s_p1[1][t];
        unsigned a2 = s_p2[0][t], b2 = s_p2[1][t];
        unsigned f1 = a1 < b1 ? a1 : b1;
        unsigned mx = a1 < b1 ? b1 : a1;
        unsigned mn2 = a2 < b2 ? a2 : b2;
        unsigned f2 = mx < mn2 ? mx : mn2;
        s_widx[t] = (int)(f1 & 1023u);
        if (f2 - f1 <= MARGIN_P) {
            int pos = atomicAdd((int*)(ws + CNT_OFF), 1);
            if (pos < LIST_CAP) ((int*)(ws + LIST_OFF))[pos] = nb + t;
        }
    }
    __syncthreads();

    // ---- gather-write (stores coalesced across rows); 512 threads, 16 d each
    {
        int r = t & 127, qd = t >> 7;                  // qd in 0..3
        int widx = s_widx[r];
        const float4* er = (const float4*)(cb + (size_t)widx * D + qd * 16);
        float* op = out + (size_t)b * (D * HW) + hw0 + r + (size_t)(qd * 16) * HW;
#pragma unroll
        for (int i = 0; i < 4; ++i) {
            float4 v = er[i];
            op[(size_t)(i * 4 + 0) * HW] = v.x;
            op[(size_t)(i * 4 + 1) * HW] = v.y;
            op[(size_t)(i * 4 + 2) * HW] = v.z;
            op[(size_t)(i * 4 + 3) * HW] = v.w;
        }
    }
}

// --- rescore: exact fp32-emulated chain over all codes for flagged vectors ---
__global__ __launch_bounds__(64) void vq_rescore(const float* __restrict__ in,
                                                 const float* __restrict__ cb,
                                                 float* __restrict__ out,
                                                 char* __restrict__ ws) {
    int count = *(const int*)(ws + CNT_OFF);
    if (count > LIST_CAP) count = LIST_CAP;
    const int* list = (const int*)(ws + LIST_OFF);
    const float* seg = (const float*)(ws + SE_OFF);
    int lane = threadIdx.x;
    for (int i = blockIdx.x; i < count; i += gridDim.x) {
        int n = list[i];
        int b = n >> 12, hw = n & (HW - 1);
        const float* xin = in + (size_t)b * (D * HW) + hw;
        float x[D];
#pragma unroll
        for (int d = 0; d < D; ++d) x[d] = xin[(size_t)d * HW];
        float y[D];
#pragma unroll
        for (int d = 0; d < D; ++d) y[d] = __fadd_rn(x[d], x[d]);
        float sx = np_sumsq64(x);
        float best = 3.4e38f; int bidx = 0;
        for (int c = 0; c < 16; ++c) {
            int k = c * 64 + lane;                      // ascending k per lane
            const float4* e4 = (const float4*)(cb + (size_t)k * D);
            float acc = 0.f;
#pragma unroll
            for (int p = 0; p < 16; ++p) {              // exact sequential chain
                float4 ev = e4[p];
                acc = __fmaf_rn(y[p * 4 + 0], ev.x, acc);
                acc = __fmaf_rn(y[p * 4 + 1], ev.y, acc);
                acc = __fmaf_rn(y[p * 4 + 2], ev.z, acc);
                acc = __fmaf_rn(y[p * 4 + 3], ev.w, acc);
            }
            float dist = __fsub_rn(__fadd_rn(sx, seg[k]), acc);
            if (dist < best) { best = dist; bidx = k; }
        }
#pragma unroll
        for (int m = 1; m < 64; m <<= 1) {              // (val, idx) lex-min
            float ob = __shfl_xor(best, m, 64);
            int oi = __shfl_xor(bidx, m, 64);
            if (ob < best || (ob == best && oi < bidx)) { best = ob; bidx = oi; }
        }
        out[(size_t)b * (D * HW) + (size_t)lane * HW + hw] = cb[(size_t)bidx * D + lane];
    }
}

extern "C" void kernel_launch(void* const* d_in, const int* in_sizes, int n_in,
                              void* d_out, int out_size, void* d_ws, size_t ws_size,
                              hipStream_t stream) {
    const float* in = (const float*)d_in[0];
    const float* cb = (const float*)d_in[1];
    float* out = (float*)d_out;
    char* ws = (char*)d_ws;

    if (ws_size < (size_t)WS_NEED) return;   // fail visibly, never OOB

    prep_cb<<<dim3(K / 256), dim3(256), 0, stream>>>(cb, ws);
    vq_main<<<dim3(NTOTAL / 128), dim3(512), 0, stream>>>(in, cb, out, ws);
    vq_rescore<<<dim3(4096), dim3(64), 0, stream>>>(in, cb, out, ws);
}

// Round 4
// 188.704 us; speedup vs baseline: 1.9532x; 1.9532x over previous
//
#include <hip/hip_runtime.h>

// VQ nearest-codebook: MFMA bf16 hi/lo filter + exact fp32-emulated rescore.
// R9:  block-shared B-frags, double-buffered LDS + global_load_lds(16B);
//      packed-uint top-2 epilogue; A = -(2x), MFMA C-init = se+1.5.
// R10: v_med3_u32 2nd-best update; v_cvt_pk_bf16_f32 A-prep.
// R11: FAILED: (512,8) split-K spilled (VGPR 32 + 1GB scratch traffic).
// R12 (this round): occupancy via SMALLER blocks, not split-K: 64-row blocks
//      (4 waves x 16 rows each), grid 2048 -> 8 blocks/CU = 32 waves/CU at
//      __launch_bounds__(256,8). Per-wave live set shrunk to fit 64 VGPR:
//      af 8, acc 4, p1/p2 4+4 (slots = r only). No merge logic needed.
//
// ref semantics (verified R2/R3/R6/R8): d[n,k] = fl(fl(sx+se) - chain),
// sx/se = numpy pairwise-8 tree of squares, chain = sequential FMA over d of
// (2x)*e, argmin first-index tie-break. Ambiguous rows (gap <= ~3.05e-5) get
// the exact fp32-emulated rescore.

#define D 64
#define K 1024
#define HW 4096
#define NTOTAL 131072

// workspace layout (bytes)
#define BF_OFF   0          // B-frags: 32 chunks * 8 frags * 64 lanes * 16B = 256 KB
#define SE_OFF   262144     // 4 KB
#define CNT_OFF  266240
#define LIST_OFF 266244
#define LIST_CAP 65536
#define WS_NEED  (266244 + LIST_CAP * 4)

// packed-gap margin: 2^17 packed units = 2^-15 = 3.05e-5 value gap.
#define MARGIN_P 131072u

typedef __attribute__((ext_vector_type(8))) short bf16x8;   // 8 bf16 = 4 VGPR
typedef __attribute__((ext_vector_type(4))) float f32x4;
typedef __attribute__((ext_vector_type(4))) unsigned int u32x4;

__device__ __forceinline__ unsigned short bf16_rne(float f) {
    unsigned u = __float_as_uint(f);
    u += 0x7fffu + ((u >> 16) & 1u);
    return (unsigned short)(u >> 16);
}
__device__ __forceinline__ float bf16_to_f(unsigned short h) {
    return __uint_as_float(((unsigned)h) << 16);
}

// HW packed f32->bf16 RNE convert: low16 = bf16(a), high16 = bf16(b).
__device__ __forceinline__ unsigned cvt_pk_bf16(float a, float b) {
    unsigned r;
    asm("v_cvt_pk_bf16_f32 %0, %1, %2" : "=v"(r) : "v"(a), "v"(b));
    return r;
}

// numpy pairwise sum, n=64
__device__ __forceinline__ float np_sumsq64(const float* v) {
    float r[8];
#pragma unroll
    for (int j = 0; j < 8; ++j) r[j] = __fmul_rn(v[j], v[j]);
#pragma unroll
    for (int i = 8; i < 64; i += 8)
#pragma unroll
        for (int j = 0; j < 8; ++j)
            r[j] = __fadd_rn(r[j], __fmul_rn(v[i + j], v[i + j]));
    float s01 = __fadd_rn(r[0], r[1]), s23 = __fadd_rn(r[2], r[3]);
    float s45 = __fadd_rn(r[4], r[5]), s67 = __fadd_rn(r[6], r[7]);
    return __fadd_rn(__fadd_rn(s01, s23), __fadd_rn(s45, s67));
}

// --- prep: codebook -> se + B-frags in lane order; also zeroes CNT ---
__global__ __launch_bounds__(256) void prep_cb(const float* __restrict__ cb,
                                               char* __restrict__ ws) {
    if (blockIdx.x == 0 && threadIdx.x == 0) *(int*)(ws + CNT_OFF) = 0;
    int k = blockIdx.x * 256 + threadIdx.x;          // grid 4*256 = 1024
    const float* e = cb + k * D;
    float v[D];
#pragma unroll
    for (int d = 0; d < D; ++d) v[d] = e[d];
    ((float*)(ws + SE_OFF))[k] = np_sumsq64(v);
    unsigned short hh[D], ll[D];
#pragma unroll
    for (int d = 0; d < D; ++d) {
        hh[d] = bf16_rne(v[d]);
        ll[d] = bf16_rne(v[d] - bf16_to_f(hh[d]));
    }
    const int c = k >> 5, tc = (k >> 4) & 1, c16 = k & 15;
    uint4* bf = (uint4*)(ws + BF_OFF);
#pragma unroll
    for (int qd = 0; qd < 8; ++qd) {                 // d0 = qd*8
        int q = qd & 3, jh = qd >> 2;                // d0 = q*8 + 32*jh
        int l = q * 16 + c16;
        uint4 a, b;
        const unsigned short* h = hh + qd * 8;
        const unsigned short* lo = ll + qd * 8;
        a.x = h[0] | (h[1] << 16);  a.y = h[2] | (h[3] << 16);
        a.z = h[4] | (h[5] << 16);  a.w = h[6] | (h[7] << 16);
        b.x = lo[0] | (lo[1] << 16); b.y = lo[2] | (lo[3] << 16);
        b.z = lo[4] | (lo[5] << 16); b.w = lo[6] | (lo[7] << 16);
        bf[(c * 8 + tc * 4 + jh) * 64 + l]       = a;   // hi -> j=jh
        bf[(c * 8 + tc * 4 + 2 + jh) * 64 + l]   = b;   // lo -> j=2+jh
    }
}

// --- main: 256 threads = 4 waves, 64 rows/block (16 rows/wave), grid 2048 ---
__global__ __launch_bounds__(256, 8) void vq_main(const float* __restrict__ in,
                                                  const float* __restrict__ cb,
                                                  float* __restrict__ out,
                                                  char* __restrict__ ws) {
    __shared__ uint4 s_bf[2][8][64];   // 16 KB double-buffered B-frag chunk
    __shared__ int s_widx[64];

    const int t = threadIdx.x;
    const int nb = blockIdx.x * 64;           // grid 2048
    const int b = nb >> 12, hw0 = nb & (HW - 1);
    const int lane = t & 63, q = lane >> 4, c16 = lane & 15, w = t >> 6;

    // ---- A-frags direct from global. A = -(2x), hi/lo split via HW cvt_pk.
    // A[m=c16][k=q*8+i], d = 32*jh + q*8 + i. Rows: w*16 + c16.
    bf16x8 af[4];
    {
        const float* xp = in + (size_t)b * (D * HW) + hw0 + w * 16 + c16;
#pragma unroll
        for (int jh = 0; jh < 2; ++jh) {
            float ny[8];
#pragma unroll
            for (int i = 0; i < 8; ++i)
                ny[i] = __fmul_rn(xp[(size_t)(jh * 32 + q * 8 + i) * HW], -2.0f);
            u32x4 hv, lv;
#pragma unroll
            for (int p = 0; p < 4; ++p) {
                unsigned hp = cvt_pk_bf16(ny[2 * p], ny[2 * p + 1]);
                float h0 = __uint_as_float(hp << 16);
                float h1 = __uint_as_float(hp & 0xFFFF0000u);
                unsigned lp = cvt_pk_bf16(__fsub_rn(ny[2 * p], h0),
                                          __fsub_rn(ny[2 * p + 1], h1));
                hv[p] = hp; lv[p] = lp;
            }
            af[jh]     = __builtin_bit_cast(bf16x8, hv);   // j=0,1: hi
            af[2 + jh] = __builtin_bit_cast(bf16x8, lv);   // j=2,3: lo
        }
    }

    const float* seg = (const float*)(ws + SE_OFF);
    const char* bfbase = ws + BF_OFF;

    unsigned p1[4], p2[4];
#pragma unroll
    for (int s = 0; s < 4; ++s) { p1[s] = 0xFFFFFFFFu; p2[s] = 0xFFFFFFFFu; }

    // stage chunk 0 into buf 0 (wave w stages frags 2w, 2w+1; lane-ordered 16B)
    {
        const char* g = bfbase + ((size_t)(0 * 8 + 2 * w) * 64 + lane) * 16;
        __builtin_amdgcn_global_load_lds((const __attribute__((address_space(1))) void*)g,
            (__attribute__((address_space(3))) void*)&s_bf[0][2 * w][0], 16, 0, 0);
        __builtin_amdgcn_global_load_lds((const __attribute__((address_space(1))) void*)(g + 1024),
            (__attribute__((address_space(3))) void*)&s_bf[0][2 * w + 1][0], 16, 0, 0);
    }
    __syncthreads();

    for (int c = 0; c < 32; ++c) {
        const int cur = c & 1;
        if (c + 1 < 32) {   // prefetch next chunk into other buffer (async)
            const char* g = bfbase + ((size_t)((c + 1) * 8 + 2 * w) * 64 + lane) * 16;
            __builtin_amdgcn_global_load_lds((const __attribute__((address_space(1))) void*)g,
                (__attribute__((address_space(3))) void*)&s_bf[cur ^ 1][2 * w][0], 16, 0, 0);
            __builtin_amdgcn_global_load_lds((const __attribute__((address_space(1))) void*)(g + 1024),
                (__attribute__((address_space(3))) void*)&s_bf[cur ^ 1][2 * w + 1][0], 16, 0, 0);
        }

        // tc-outer keeps bfr/acc live-sets small (fit 8 waves/SIMD budget)
#pragma unroll
        for (int tc = 0; tc < 2; ++tc) {
            float sec = __fadd_rn(seg[c * 32 + tc * 16 + c16], 1.5f);

            bf16x8 bfr[4];
#pragma unroll
            for (int j = 0; j < 4; ++j)
                bfr[j] = *(const bf16x8*)&s_bf[cur][tc * 4 + j][lane];

            f32x4 acc = (f32x4){sec, sec, sec, sec};

            // K=192: (-yh)*eh (2) + (-yl)*eh (2) + (-yh)*el (2) on se'
            const int sa[6] = {0, 1, 2, 3, 0, 1};
            const int sb[6] = {0, 1, 0, 1, 2, 3};
#pragma unroll
            for (int s = 0; s < 6; ++s)
                acc = __builtin_amdgcn_mfma_f32_16x16x32_bf16(
                    af[sa[s]], bfr[sb[s]], acc, 0, 0, 0);

            // epilogue: p = ((bits>>1)<<10) | code; p2'=med3(p,p1,p2), p1'=min
            unsigned code = (unsigned)(c * 32 + tc * 16 + c16);
#pragma unroll
            for (int r = 0; r < 4; ++r) {
                unsigned u = __float_as_uint(acc[r]);
                unsigned p = ((u >> 1) << 10) | code;
                unsigned m;
                asm("v_med3_u32 %0, %1, %2, %3"
                    : "=v"(m) : "v"(p), "v"(p1[r]), "v"(p2[r]));
                p2[r] = m;
                p1[r] = p < p1[r] ? p : p1[r];
            }
        }
        __syncthreads();   // all waves done with buf cur; prefetch drained
    }

    // ---- cross-lane top-2 merge over the 16 col-lanes (bits 0-3 of lane)
#pragma unroll
    for (int m = 1; m < 16; m <<= 1)
#pragma unroll
        for (int s = 0; s < 4; ++s) {
            unsigned o1 = (unsigned)__shfl_xor((int)p1[s], m, 64);
            unsigned o2 = (unsigned)__shfl_xor((int)p2[s], m, 64);
            unsigned lo = p1[s] < o1 ? p1[s] : o1;
            unsigned hi = p1[s] < o1 ? o1 : p1[s];
            unsigned n2 = p2[s] < o2 ? p2[s] : o2;
            p2[s] = hi < n2 ? hi : n2;
            p1[s] = lo;
        }

    if (c16 == 0) {
#pragma unroll
        for (int s = 0; s < 4; ++s) {
            int row = w * 16 + q * 4 + s;              // block-local
            s_widx[row] = (int)(p1[s] & 1023u);
            if (p2[s] - p1[s] <= MARGIN_P) {
                int pos = atomicAdd((int*)(ws + CNT_OFF), 1);
                if (pos < LIST_CAP) ((int*)(ws + LIST_OFF))[pos] = nb + row;
            }
        }
    }
    __syncthreads();

    // ---- gather-write: 64 rows x 64 d by 256 threads (16 d each)
    {
        int r = t & 63, qd = t >> 6;                   // qd in 0..3
        int widx = s_widx[r];
        const float4* er = (const float4*)(cb + (size_t)widx * D + qd * 16);
        float* op = out + (size_t)b * (D * HW) + hw0 + r + (size_t)(qd * 16) * HW;
#pragma unroll
        for (int i = 0; i < 4; ++i) {
            float4 v = er[i];
            op[(size_t)(i * 4 + 0) * HW] = v.x;
            op[(size_t)(i * 4 + 1) * HW] = v.y;
            op[(size_t)(i * 4 + 2) * HW] = v.z;
            op[(size_t)(i * 4 + 3) * HW] = v.w;
        }
    }
}

// --- rescore: exact fp32-emulated chain over all codes for flagged vectors ---
__global__ __launch_bounds__(64) void vq_rescore(const float* __restrict__ in,
                                                 const float* __restrict__ cb,
                                                 float* __restrict__ out,
                                                 char* __restrict__ ws) {
    int count = *(const int*)(ws + CNT_OFF);
    if (count > LIST_CAP) count = LIST_CAP;
    const int* list = (const int*)(ws + LIST_OFF);
    const float* seg = (const float*)(ws + SE_OFF);
    int lane = threadIdx.x;
    for (int i = blockIdx.x; i < count; i += gridDim.x) {
        int n = list[i];
        int b = n >> 12, hw = n & (HW - 1);
        const float* xin = in + (size_t)b * (D * HW) + hw;
        float x[D];
#pragma unroll
        for (int d = 0; d < D; ++d) x[d] = xin[(size_t)d * HW];
        float y[D];
#pragma unroll
        for (int d = 0; d < D; ++d) y[d] = __fadd_rn(x[d], x[d]);
        float sx = np_sumsq64(x);
        float best = 3.4e38f; int bidx = 0;
        for (int c = 0; c < 16; ++c) {
            int k = c * 64 + lane;                      // ascending k per lane
            const float4* e4 = (const float4*)(cb + (size_t)k * D);
            float acc = 0.f;
#pragma unroll
            for (int p = 0; p < 16; ++p) {              // exact sequential chain
                float4 ev = e4[p];
                acc = __fmaf_rn(y[p * 4 + 0], ev.x, acc);
                acc = __fmaf_rn(y[p * 4 + 1], ev.y, acc);
                acc = __fmaf_rn(y[p * 4 + 2], ev.z, acc);
                acc = __fmaf_rn(y[p * 4 + 3], ev.w, acc);
            }
            float dist = __fsub_rn(__fadd_rn(sx, seg[k]), acc);
            if (dist < best) { best = dist; bidx = k; }
        }
#pragma unroll
        for (int m = 1; m < 64; m <<= 1) {              // (val, idx) lex-min
            float ob = __shfl_xor(best, m, 64);
            int oi = __shfl_xor(bidx, m, 64);
            if (ob < best || (ob == best && oi < bidx)) { best = ob; bidx = oi; }
        }
        out[(size_t)b * (D * HW) + (size_t)lane * HW + hw] = cb[(size_t)bidx * D + lane];
    }
}

extern "C" void kernel_launch(void* const* d_in, const int* in_sizes, int n_in,
                              void* d_out, int out_size, void* d_ws, size_t ws_size,
                              hipStream_t stream) {
    const float* in = (const float*)d_in[0];
    const float* cb = (const float*)d_in[1];
    float* out = (float*)d_out;
    char* ws = (char*)d_ws;

    if (ws_size < (size_t)WS_NEED) return;   // fail visibly, never OOB

    prep_cb<<<dim3(K / 256), dim3(256), 0, stream>>>(cb, ws);
    vq_main<<<dim3(NTOTAL / 64), dim3(256), 0, stream>>>(in, cb, out, ws);
    vq_rescore<<<dim3(1024), dim3(64), 0, stream>>>(in, cb, out, ws);
}

// Round 5
// 183.278 us; speedup vs baseline: 2.0110x; 1.0296x over previous
//
#include <hip/hip_runtime.h>

// VQ nearest-codebook: MFMA bf16 hi/lo filter + exact fp32-emulated rescore.
// R9:  block-shared B-frags, dbuf LDS + global_load_lds(16B); packed top-2.
// R10: v_med3_u32 2nd-best; v_cvt_pk_bf16_f32 A-prep.
// R11: FAILED (512,8) split-K: spilled. R12: 32 waves/CU neutral -> not
//      latency-bound; wall = serial per-chunk chain (LDS burst -> MFMA ->
//      epilogue -> barrier), all waves in lockstep.
// R13 (this round): break the serial chain. 128-row blocks (32 rows/wave,
//      halves LDS traffic per MFMA vs R12) + DEFERRED EPILOGUE: chunk c's
//      top-2 VALU is placed between ds_read issue and MFMAs of chunk c+1,
//      so it executes in the ds-latency + MFMA-pipe shadow (in-order issue).
//      Even/odd unrolled pipeline keeps acc/buf indices static. se+1.5
//      precomputed in prep (SE2); rescore keeps raw SE for exact ref math.
//
// ref semantics (verified R2/R3/R6/R8): d[n,k] = fl(fl(sx+se) - chain),
// sx/se = numpy pairwise-8 tree of squares, chain = sequential FMA over d of
// (2x)*e, argmin first-index tie-break. Ambiguous rows (gap <= ~3.05e-5) get
// the exact fp32-emulated rescore.

#define D 64
#define K 1024
#define HW 4096
#define NTOTAL 131072

// workspace layout (bytes)
#define BF_OFF   0          // B-frags: 32 chunks * 8 frags * 64 lanes * 16B = 256 KB
#define SE_OFF   262144     // 4 KB raw se (rescore)
#define SE2_OFF  266240     // 4 KB se+1.5 (main C-init)
#define CNT_OFF  270336
#define LIST_OFF 270340
#define LIST_CAP 65536
#define WS_NEED  (270340 + LIST_CAP * 4)

// packed-gap margin: 2^17 packed units = 2^-15 = 3.05e-5 value gap.
#define MARGIN_P 131072u

typedef __attribute__((ext_vector_type(8))) short bf16x8;   // 8 bf16 = 4 VGPR
typedef __attribute__((ext_vector_type(4))) float f32x4;
typedef __attribute__((ext_vector_type(4))) unsigned int u32x4;

__device__ __forceinline__ unsigned short bf16_rne(float f) {
    unsigned u = __float_as_uint(f);
    u += 0x7fffu + ((u >> 16) & 1u);
    return (unsigned short)(u >> 16);
}
__device__ __forceinline__ float bf16_to_f(unsigned short h) {
    return __uint_as_float(((unsigned)h) << 16);
}

// HW packed f32->bf16 RNE convert: low16 = bf16(a), high16 = bf16(b).
__device__ __forceinline__ unsigned cvt_pk_bf16(float a, float b) {
    unsigned r;
    asm("v_cvt_pk_bf16_f32 %0, %1, %2" : "=v"(r) : "v"(a), "v"(b));
    return r;
}

// numpy pairwise sum, n=64
__device__ __forceinline__ float np_sumsq64(const float* v) {
    float r[8];
#pragma unroll
    for (int j = 0; j < 8; ++j) r[j] = __fmul_rn(v[j], v[j]);
#pragma unroll
    for (int i = 8; i < 64; i += 8)
#pragma unroll
        for (int j = 0; j < 8; ++j)
            r[j] = __fadd_rn(r[j], __fmul_rn(v[i + j], v[i + j]));
    float s01 = __fadd_rn(r[0], r[1]), s23 = __fadd_rn(r[2], r[3]);
    float s45 = __fadd_rn(r[4], r[5]), s67 = __fadd_rn(r[6], r[7]);
    return __fadd_rn(__fadd_rn(s01, s23), __fadd_rn(s45, s67));
}

// --- prep: codebook -> se, se+1.5, B-frags in lane order; zeroes CNT ---
__global__ __launch_bounds__(256) void prep_cb(const float* __restrict__ cb,
                                               char* __restrict__ ws) {
    if (blockIdx.x == 0 && threadIdx.x == 0) *(int*)(ws + CNT_OFF) = 0;
    int k = blockIdx.x * 256 + threadIdx.x;          // grid 4*256 = 1024
    const float* e = cb + k * D;
    float v[D];
#pragma unroll
    for (int d = 0; d < D; ++d) v[d] = e[d];
    float se = np_sumsq64(v);
    ((float*)(ws + SE_OFF))[k] = se;
    ((float*)(ws + SE2_OFF))[k] = __fadd_rn(se, 1.5f);
    unsigned short hh[D], ll[D];
#pragma unroll
    for (int d = 0; d < D; ++d) {
        hh[d] = bf16_rne(v[d]);
        ll[d] = bf16_rne(v[d] - bf16_to_f(hh[d]));
    }
    const int c = k >> 5, tc = (k >> 4) & 1, c16 = k & 15;
    uint4* bf = (uint4*)(ws + BF_OFF);
#pragma unroll
    for (int qd = 0; qd < 8; ++qd) {                 // d0 = qd*8
        int q = qd & 3, jh = qd >> 2;                // d0 = q*8 + 32*jh
        int l = q * 16 + c16;
        uint4 a, b;
        const unsigned short* h = hh + qd * 8;
        const unsigned short* lo = ll + qd * 8;
        a.x = h[0] | (h[1] << 16);  a.y = h[2] | (h[3] << 16);
        a.z = h[4] | (h[5] << 16);  a.w = h[6] | (h[7] << 16);
        b.x = lo[0] | (lo[1] << 16); b.y = lo[2] | (lo[3] << 16);
        b.z = lo[4] | (lo[5] << 16); b.w = lo[6] | (lo[7] << 16);
        bf[(c * 8 + tc * 4 + jh) * 64 + l]       = a;   // hi -> j=jh
        bf[(c * 8 + tc * 4 + 2 + jh) * 64 + l]   = b;   // lo -> j=2+jh
    }
}

// --- main: 256 threads = 4 waves, 128 rows/block (32 rows/wave), grid 1024 ---
__global__ __launch_bounds__(256, 4) void vq_main(const float* __restrict__ in,
                                                  const float* __restrict__ cb,
                                                  float* __restrict__ out,
                                                  char* __restrict__ ws) {
    __shared__ uint4 s_bf[2][8][64];   // 16 KB double-buffered B-frag chunk
    __shared__ int s_widx[128];

    const int t = threadIdx.x;
    const int nb = blockIdx.x * 128;          // grid 1024
    const int b = nb >> 12, hw0 = nb & (HW - 1);
    const int lane = t & 63, q = lane >> 4, c16 = lane & 15, w = t >> 6;

    // ---- A-frags direct from global. A = -(2x), hi/lo split via HW cvt_pk.
    // A[m=c16][k=q*8+i], d = 32*jh + q*8 + i. Rows: w*32 + tv*16 + c16.
    bf16x8 af[2][4];
#pragma unroll
    for (int tv = 0; tv < 2; ++tv) {
        const float* xp = in + (size_t)b * (D * HW) + hw0 + w * 32 + tv * 16 + c16;
#pragma unroll
        for (int jh = 0; jh < 2; ++jh) {
            float ny[8];
#pragma unroll
            for (int i = 0; i < 8; ++i)
                ny[i] = __fmul_rn(xp[(size_t)(jh * 32 + q * 8 + i) * HW], -2.0f);
            u32x4 hv, lv;
#pragma unroll
            for (int p = 0; p < 4; ++p) {
                unsigned hp = cvt_pk_bf16(ny[2 * p], ny[2 * p + 1]);
                float h0 = __uint_as_float(hp << 16);
                float h1 = __uint_as_float(hp & 0xFFFF0000u);
                unsigned lp = cvt_pk_bf16(__fsub_rn(ny[2 * p], h0),
                                          __fsub_rn(ny[2 * p + 1], h1));
                hv[p] = hp; lv[p] = lp;
            }
            af[tv][jh]     = __builtin_bit_cast(bf16x8, hv);   // j=0,1: hi
            af[tv][2 + jh] = __builtin_bit_cast(bf16x8, lv);   // j=2,3: lo
        }
    }

    const float* seg2 = (const float*)(ws + SE2_OFF);
    const char* bfbase = ws + BF_OFF;

    unsigned p1[8], p2[8];
#pragma unroll
    for (int s = 0; s < 8; ++s) { p1[s] = 0xFFFFFFFFu; p2[s] = 0xFFFFFFFFu; }

    // pipeline helpers (all args compile-time after inlining)
    auto stage_chunk = [&](int c, int buf) {
        const char* g = bfbase + ((size_t)(c * 8 + 2 * w) * 64 + lane) * 16;
        __builtin_amdgcn_global_load_lds((const __attribute__((address_space(1))) void*)g,
            (__attribute__((address_space(3))) void*)&s_bf[buf][2 * w][0], 16, 0, 0);
        __builtin_amdgcn_global_load_lds((const __attribute__((address_space(1))) void*)(g + 1024),
            (__attribute__((address_space(3))) void*)&s_bf[buf][2 * w + 1][0], 16, 0, 0);
    };
    auto epilogue = [&](int c, const f32x4 (&acc)[2][2]) {
#pragma unroll
        for (int tv = 0; tv < 2; ++tv)
#pragma unroll
            for (int tc = 0; tc < 2; ++tc) {
                unsigned code = (unsigned)(c * 32 + tc * 16 + c16);
#pragma unroll
                for (int r = 0; r < 4; ++r) {
                    unsigned u = __float_as_uint(acc[tv][tc][r]);
                    unsigned p = ((u >> 1) << 10) | code;
                    int s = tv * 4 + r;
                    unsigned m;
                    asm("v_med3_u32 %0, %1, %2, %3"
                        : "=v"(m) : "v"(p), "v"(p1[s]), "v"(p2[s]));
                    p2[s] = m;
                    p1[s] = p < p1[s] ? p : p1[s];
                }
            }
    };
    const int sa[6] = {0, 1, 2, 3, 0, 1};
    const int sb[6] = {0, 1, 0, 1, 2, 3};

    f32x4 accE[2][2], accO[2][2];
    bf16x8 bfr[2][4];

    // prologue: stage chunk 0 into buf 0
    stage_chunk(0, 0);
    __syncthreads();

    for (int i = 0; i < 16; ++i) {
        const int ce = 2 * i, co = 2 * i + 1;

        // ---- even phase: compute ce from buf0; epilogue(ce-1) in its shadow
        stage_chunk(co, 1);                       // prefetch odd -> buf1
        {
            // issue all ds_reads first (no wait yet)
#pragma unroll
            for (int tc = 0; tc < 2; ++tc)
#pragma unroll
                for (int j = 0; j < 4; ++j)
                    bfr[tc][j] = *(const bf16x8*)&s_bf[0][tc * 4 + j][lane];
            // acc init (VALU, fills ds latency)
#pragma unroll
            for (int tc = 0; tc < 2; ++tc) {
                float sec = seg2[ce * 32 + tc * 16 + c16];
#pragma unroll
                for (int tv = 0; tv < 2; ++tv)
                    accE[tv][tc] = (f32x4){sec, sec, sec, sec};
            }
            // deferred epilogue of previous odd chunk (VALU in MFMA/ds shadow)
            if (i != 0) epilogue(ce - 1, accO);
            // MFMAs (lgkm wait lands here)
#pragma unroll
            for (int s = 0; s < 6; ++s)
#pragma unroll
                for (int tv = 0; tv < 2; ++tv)
#pragma unroll
                    for (int tc = 0; tc < 2; ++tc)
                        accE[tv][tc] = __builtin_amdgcn_mfma_f32_16x16x32_bf16(
                            af[tv][sa[s]], bfr[tc][sb[s]], accE[tv][tc], 0, 0, 0);
        }
        __syncthreads();                          // buf1 staged; buf0 reads done

        // ---- odd phase: compute co from buf1; epilogue(ce) in its shadow
        if (i < 15) stage_chunk(ce + 2, 0);       // prefetch next even -> buf0
        {
#pragma unroll
            for (int tc = 0; tc < 2; ++tc)
#pragma unroll
                for (int j = 0; j < 4; ++j)
                    bfr[tc][j] = *(const bf16x8*)&s_bf[1][tc * 4 + j][lane];
#pragma unroll
            for (int tc = 0; tc < 2; ++tc) {
                float sec = seg2[co * 32 + tc * 16 + c16];
#pragma unroll
                for (int tv = 0; tv < 2; ++tv)
                    accO[tv][tc] = (f32x4){sec, sec, sec, sec};
            }
            epilogue(ce, accE);
#pragma unroll
            for (int s = 0; s < 6; ++s)
#pragma unroll
                for (int tv = 0; tv < 2; ++tv)
#pragma unroll
                    for (int tc = 0; tc < 2; ++tc)
                        accO[tv][tc] = __builtin_amdgcn_mfma_f32_16x16x32_bf16(
                            af[tv][sa[s]], bfr[tc][sb[s]], accO[tv][tc], 0, 0, 0);
        }
        __syncthreads();                          // buf0 staged; buf1 reads done
    }
    epilogue(31, accO);

    // ---- cross-lane top-2 merge over the 16 col-lanes (bits 0-3 of lane)
#pragma unroll
    for (int m = 1; m < 16; m <<= 1)
#pragma unroll
        for (int s = 0; s < 8; ++s) {
            unsigned o1 = (unsigned)__shfl_xor((int)p1[s], m, 64);
            unsigned o2 = (unsigned)__shfl_xor((int)p2[s], m, 64);
            unsigned lo = p1[s] < o1 ? p1[s] : o1;
            unsigned hi = p1[s] < o1 ? o1 : p1[s];
            unsigned n2 = p2[s] < o2 ? p2[s] : o2;
            p2[s] = hi < n2 ? hi : n2;
            p1[s] = lo;
        }

    if (c16 == 0) {
#pragma unroll
        for (int s = 0; s < 8; ++s) {
            int tv = s >> 2, r = s & 3;
            int row = w * 32 + tv * 16 + q * 4 + r;    // block-local
            s_widx[row] = (int)(p1[s] & 1023u);
            if (p2[s] - p1[s] <= MARGIN_P) {
                int pos = atomicAdd((int*)(ws + CNT_OFF), 1);
                if (pos < LIST_CAP) ((int*)(ws + LIST_OFF))[pos] = nb + row;
            }
        }
    }
    __syncthreads();

    // ---- gather-write (stores coalesced across rows)
    {
        int r = t & 127, half = t >> 7;
        int widx = s_widx[r];
        const float4* er = (const float4*)(cb + (size_t)widx * D + half * 32);
        float* op = out + (size_t)b * (D * HW) + hw0 + r + (size_t)(half * 32) * HW;
#pragma unroll
        for (int i = 0; i < 8; ++i) {
            float4 v = er[i];
            op[(size_t)(i * 4 + 0) * HW] = v.x;
            op[(size_t)(i * 4 + 1) * HW] = v.y;
            op[(size_t)(i * 4 + 2) * HW] = v.z;
            op[(size_t)(i * 4 + 3) * HW] = v.w;
        }
    }
}

// --- rescore: exact fp32-emulated chain over all codes for flagged vectors ---
__global__ __launch_bounds__(64) void vq_rescore(const float* __restrict__ in,
                                                 const float* __restrict__ cb,
                                                 float* __restrict__ out,
                                                 char* __restrict__ ws) {
    int count = *(const int*)(ws + CNT_OFF);
    if (count > LIST_CAP) count = LIST_CAP;
    const int* list = (const int*)(ws + LIST_OFF);
    const float* seg = (const float*)(ws + SE_OFF);
    int lane = threadIdx.x;
    for (int i = blockIdx.x; i < count; i += gridDim.x) {
        int n = list[i];
        int b = n >> 12, hw = n & (HW - 1);
        const float* xin = in + (size_t)b * (D * HW) + hw;
        float x[D];
#pragma unroll
        for (int d = 0; d < D; ++d) x[d] = xin[(size_t)d * HW];
        float y[D];
#pragma unroll
        for (int d = 0; d < D; ++d) y[d] = __fadd_rn(x[d], x[d]);
        float sx = np_sumsq64(x);
        float best = 3.4e38f; int bidx = 0;
        for (int c = 0; c < 16; ++c) {
            int k = c * 64 + lane;                      // ascending k per lane
            const float4* e4 = (const float4*)(cb + (size_t)k * D);
            float acc = 0.f;
#pragma unroll
            for (int p = 0; p < 16; ++p) {              // exact sequential chain
                float4 ev = e4[p];
                acc = __fmaf_rn(y[p * 4 + 0], ev.x, acc);
                acc = __fmaf_rn(y[p * 4 + 1], ev.y, acc);
                acc = __fmaf_rn(y[p * 4 + 2], ev.z, acc);
                acc = __fmaf_rn(y[p * 4 + 3], ev.w, acc);
            }
            float dist = __fsub_rn(__fadd_rn(sx, seg[k]), acc);
            if (dist < best) { best = dist; bidx = k; }
        }
#pragma unroll
        for (int m = 1; m < 64; m <<= 1) {              // (val, idx) lex-min
            float ob = __shfl_xor(best, m, 64);
            int oi = __shfl_xor(bidx, m, 64);
            if (ob < best || (ob == best && oi < bidx)) { best = ob; bidx = oi; }
        }
        out[(size_t)b * (D * HW) + (size_t)lane * HW + hw] = cb[(size_t)bidx * D + lane];
    }
}

extern "C" void kernel_launch(void* const* d_in, const int* in_sizes, int n_in,
                              void* d_out, int out_size, void* d_ws, size_t ws_size,
                              hipStream_t stream) {
    const float* in = (const float*)d_in[0];
    const float* cb = (const float*)d_in[1];
    float* out = (float*)d_out;
    char* ws = (char*)d_ws;

    if (ws_size < (size_t)WS_NEED) return;   // fail visibly, never OOB

    prep_cb<<<dim3(K / 256), dim3(256), 0, stream>>>(cb, ws);
    vq_main<<<dim3(NTOTAL / 128), dim3(256), 0, stream>>>(in, cb, out, ws);
    vq_rescore<<<dim3(1024), dim3(64), 0, stream>>>(in, cb, out, ws);
}

// Round 6
// 182.011 us; speedup vs baseline: 2.0250x; 1.0070x over previous
//
#include <hip/hip_runtime.h>

// VQ nearest-codebook: MFMA bf16 hi/lo filter + exact fp32-emulated rescore.
// R9:  block-shared B-frags, dbuf LDS + global_load_lds(16B); packed top-2.
// R10: v_med3_u32 2nd-best; v_cvt_pk_bf16_f32 A-prep.
// R11: FAILED split-K (spill). R12: 32 waves/CU neutral. R13: deferred
//      epilogue -12%.
// R14 (this round): three-pipe serialization diagnosis — MFMA ~25us + VALU
//      ~24us + LDS ~20us ~= 66us wall: barrier-per-half-chunk keeps waves in
//      lockstep, so the block uses one pipe at a time. PAIR-BARRIER: stage &
//      compute 2 chunks per barrier (4 LDS bufs, 32KB), barriers 64 -> 16;
//      LDS-serialization stagger persists across the pair so waves overlap
//      ds_read / MFMA / epilogue across pipes.
//
// ref semantics (verified R2/R3/R6/R8): d[n,k] = fl(fl(sx+se) - chain),
// sx/se = numpy pairwise-8 tree of squares, chain = sequential FMA over d of
// (2x)*e, argmin first-index tie-break. Ambiguous rows (gap <= ~3.05e-5) get
// the exact fp32-emulated rescore.

#define D 64
#define K 1024
#define HW 4096
#define NTOTAL 131072

// workspace layout (bytes)
#define BF_OFF   0          // B-frags: 32 chunks * 8 frags * 64 lanes * 16B = 256 KB
#define SE_OFF   262144     // 4 KB raw se (rescore)
#define SE2_OFF  266240     // 4 KB se+1.5 (main C-init)
#define CNT_OFF  270336
#define LIST_OFF 270340
#define LIST_CAP 65536
#define WS_NEED  (270340 + LIST_CAP * 4)

// packed-gap margin: 2^17 packed units = 2^-15 = 3.05e-5 value gap.
#define MARGIN_P 131072u

typedef __attribute__((ext_vector_type(8))) short bf16x8;   // 8 bf16 = 4 VGPR
typedef __attribute__((ext_vector_type(4))) float f32x4;
typedef __attribute__((ext_vector_type(4))) unsigned int u32x4;

__device__ __forceinline__ unsigned short bf16_rne(float f) {
    unsigned u = __float_as_uint(f);
    u += 0x7fffu + ((u >> 16) & 1u);
    return (unsigned short)(u >> 16);
}
__device__ __forceinline__ float bf16_to_f(unsigned short h) {
    return __uint_as_float(((unsigned)h) << 16);
}

// HW packed f32->bf16 RNE convert: low16 = bf16(a), high16 = bf16(b).
__device__ __forceinline__ unsigned cvt_pk_bf16(float a, float b) {
    unsigned r;
    asm("v_cvt_pk_bf16_f32 %0, %1, %2" : "=v"(r) : "v"(a), "v"(b));
    return r;
}

// numpy pairwise sum, n=64
__device__ __forceinline__ float np_sumsq64(const float* v) {
    float r[8];
#pragma unroll
    for (int j = 0; j < 8; ++j) r[j] = __fmul_rn(v[j], v[j]);
#pragma unroll
    for (int i = 8; i < 64; i += 8)
#pragma unroll
        for (int j = 0; j < 8; ++j)
            r[j] = __fadd_rn(r[j], __fmul_rn(v[i + j], v[i + j]));
    float s01 = __fadd_rn(r[0], r[1]), s23 = __fadd_rn(r[2], r[3]);
    float s45 = __fadd_rn(r[4], r[5]), s67 = __fadd_rn(r[6], r[7]);
    return __fadd_rn(__fadd_rn(s01, s23), __fadd_rn(s45, s67));
}

// --- prep: codebook -> se, se+1.5, B-frags in lane order; zeroes CNT ---
__global__ __launch_bounds__(256) void prep_cb(const float* __restrict__ cb,
                                               char* __restrict__ ws) {
    if (blockIdx.x == 0 && threadIdx.x == 0) *(int*)(ws + CNT_OFF) = 0;
    int k = blockIdx.x * 256 + threadIdx.x;          // grid 4*256 = 1024
    const float* e = cb + k * D;
    float v[D];
#pragma unroll
    for (int d = 0; d < D; ++d) v[d] = e[d];
    float se = np_sumsq64(v);
    ((float*)(ws + SE_OFF))[k] = se;
    ((float*)(ws + SE2_OFF))[k] = __fadd_rn(se, 1.5f);
    unsigned short hh[D], ll[D];
#pragma unroll
    for (int d = 0; d < D; ++d) {
        hh[d] = bf16_rne(v[d]);
        ll[d] = bf16_rne(v[d] - bf16_to_f(hh[d]));
    }
    const int c = k >> 5, tc = (k >> 4) & 1, c16 = k & 15;
    uint4* bf = (uint4*)(ws + BF_OFF);
#pragma unroll
    for (int qd = 0; qd < 8; ++qd) {                 // d0 = qd*8
        int q = qd & 3, jh = qd >> 2;                // d0 = q*8 + 32*jh
        int l = q * 16 + c16;
        uint4 a, b;
        const unsigned short* h = hh + qd * 8;
        const unsigned short* lo = ll + qd * 8;
        a.x = h[0] | (h[1] << 16);  a.y = h[2] | (h[3] << 16);
        a.z = h[4] | (h[5] << 16);  a.w = h[6] | (h[7] << 16);
        b.x = lo[0] | (lo[1] << 16); b.y = lo[2] | (lo[3] << 16);
        b.z = lo[4] | (lo[5] << 16); b.w = lo[6] | (lo[7] << 16);
        bf[(c * 8 + tc * 4 + jh) * 64 + l]       = a;   // hi -> j=jh
        bf[(c * 8 + tc * 4 + 2 + jh) * 64 + l]   = b;   // lo -> j=2+jh
    }
}

// --- main: 256 threads = 4 waves, 128 rows/block (32 rows/wave), grid 1024 ---
__global__ __launch_bounds__(256, 4) void vq_main(const float* __restrict__ in,
                                                  const float* __restrict__ cb,
                                                  float* __restrict__ out,
                                                  char* __restrict__ ws) {
    __shared__ uint4 s_bf[2][2][8][64];   // [set][chunk-in-pair][frag][lane] = 32 KB
    __shared__ int s_widx[128];

    const int t = threadIdx.x;
    const int nb = blockIdx.x * 128;          // grid 1024
    const int b = nb >> 12, hw0 = nb & (HW - 1);
    const int lane = t & 63, q = lane >> 4, c16 = lane & 15, w = t >> 6;

    // ---- A-frags direct from global. A = -(2x), hi/lo split via HW cvt_pk.
    // A[m=c16][k=q*8+i], d = 32*jh + q*8 + i. Rows: w*32 + tv*16 + c16.
    bf16x8 af[2][4];
#pragma unroll
    for (int tv = 0; tv < 2; ++tv) {
        const float* xp = in + (size_t)b * (D * HW) + hw0 + w * 32 + tv * 16 + c16;
#pragma unroll
        for (int jh = 0; jh < 2; ++jh) {
            float ny[8];
#pragma unroll
            for (int i = 0; i < 8; ++i)
                ny[i] = __fmul_rn(xp[(size_t)(jh * 32 + q * 8 + i) * HW], -2.0f);
            u32x4 hv, lv;
#pragma unroll
            for (int p = 0; p < 4; ++p) {
                unsigned hp = cvt_pk_bf16(ny[2 * p], ny[2 * p + 1]);
                float h0 = __uint_as_float(hp << 16);
                float h1 = __uint_as_float(hp & 0xFFFF0000u);
                unsigned lp = cvt_pk_bf16(__fsub_rn(ny[2 * p], h0),
                                          __fsub_rn(ny[2 * p + 1], h1));
                hv[p] = hp; lv[p] = lp;
            }
            af[tv][jh]     = __builtin_bit_cast(bf16x8, hv);   // j=0,1: hi
            af[tv][2 + jh] = __builtin_bit_cast(bf16x8, lv);   // j=2,3: lo
        }
    }

    const float* seg2 = (const float*)(ws + SE2_OFF);
    const char* bfbase = ws + BF_OFF;

    unsigned p1[8], p2[8];
#pragma unroll
    for (int s = 0; s < 8; ++s) { p1[s] = 0xFFFFFFFFu; p2[s] = 0xFFFFFFFFu; }

    // stage one chunk into [set][u] (wave w stages frags 2w, 2w+1)
    auto stage_chunk = [&](int c, int set, int u) {
        const char* g = bfbase + ((size_t)(c * 8 + 2 * w) * 64 + lane) * 16;
        __builtin_amdgcn_global_load_lds((const __attribute__((address_space(1))) void*)g,
            (__attribute__((address_space(3))) void*)&s_bf[set][u][2 * w][0], 16, 0, 0);
        __builtin_amdgcn_global_load_lds((const __attribute__((address_space(1))) void*)(g + 1024),
            (__attribute__((address_space(3))) void*)&s_bf[set][u][2 * w + 1][0], 16, 0, 0);
    };
    auto epilogue = [&](int c, const f32x4 (&acc)[2][2]) {
#pragma unroll
        for (int tv = 0; tv < 2; ++tv)
#pragma unroll
            for (int tc = 0; tc < 2; ++tc) {
                unsigned code = (unsigned)(c * 32 + tc * 16 + c16);
#pragma unroll
                for (int r = 0; r < 4; ++r) {
                    unsigned u = __float_as_uint(acc[tv][tc][r]);
                    unsigned p = ((u >> 1) << 10) | code;
                    int s = tv * 4 + r;
                    unsigned m;
                    asm("v_med3_u32 %0, %1, %2, %3"
                        : "=v"(m) : "v"(p), "v"(p1[s]), "v"(p2[s]));
                    p2[s] = m;
                    p1[s] = p < p1[s] ? p : p1[s];
                }
            }
    };
    const int sa[6] = {0, 1, 2, 3, 0, 1};
    const int sb[6] = {0, 1, 0, 1, 2, 3};

    f32x4 accE[2][2], accO[2][2];
    bf16x8 bfr[2][4];

    // prologue: stage pair 0 into set 0
    stage_chunk(0, 0, 0);
    stage_chunk(1, 0, 1);
    __syncthreads();

    int set = 0;
    for (int p = 0; p < 16; ++p) {
        const int ce = 2 * p, co = 2 * p + 1;

        // prefetch next pair into the other set (drained by the pair barrier)
        if (p < 15) {
            stage_chunk(ce + 2, set ^ 1, 0);
            stage_chunk(co + 2, set ^ 1, 1);
        }

        // ---- chunk ce (even): reads + acc init + deferred epi(co-1) + MFMAs
        {
#pragma unroll
            for (int tc = 0; tc < 2; ++tc)
#pragma unroll
                for (int j = 0; j < 4; ++j)
                    bfr[tc][j] = *(const bf16x8*)&s_bf[set][0][tc * 4 + j][lane];
#pragma unroll
            for (int tc = 0; tc < 2; ++tc) {
                float sec = seg2[ce * 32 + tc * 16 + c16];
#pragma unroll
                for (int tv = 0; tv < 2; ++tv)
                    accE[tv][tc] = (f32x4){sec, sec, sec, sec};
            }
            if (p != 0) epilogue(ce - 1, accO);
#pragma unroll
            for (int s = 0; s < 6; ++s)
#pragma unroll
                for (int tv = 0; tv < 2; ++tv)
#pragma unroll
                    for (int tc = 0; tc < 2; ++tc)
                        accE[tv][tc] = __builtin_amdgcn_mfma_f32_16x16x32_bf16(
                            af[tv][sa[s]], bfr[tc][sb[s]], accE[tv][tc], 0, 0, 0);
        }

        // ---- chunk co (odd): no barrier between the two chunks of a pair
        {
#pragma unroll
            for (int tc = 0; tc < 2; ++tc)
#pragma unroll
                for (int j = 0; j < 4; ++j)
                    bfr[tc][j] = *(const bf16x8*)&s_bf[set][1][tc * 4 + j][lane];
#pragma unroll
            for (int tc = 0; tc < 2; ++tc) {
                float sec = seg2[co * 32 + tc * 16 + c16];
#pragma unroll
                for (int tv = 0; tv < 2; ++tv)
                    accO[tv][tc] = (f32x4){sec, sec, sec, sec};
            }
            epilogue(ce, accE);
#pragma unroll
            for (int s = 0; s < 6; ++s)
#pragma unroll
                for (int tv = 0; tv < 2; ++tv)
#pragma unroll
                    for (int tc = 0; tc < 2; ++tc)
                        accO[tv][tc] = __builtin_amdgcn_mfma_f32_16x16x32_bf16(
                            af[tv][sa[s]], bfr[tc][sb[s]], accO[tv][tc], 0, 0, 0);
        }

        __syncthreads();   // pair barrier: next-pair staging drained; set free
        set ^= 1;
    }
    epilogue(31, accO);

    // ---- cross-lane top-2 merge over the 16 col-lanes (bits 0-3 of lane)
#pragma unroll
    for (int m = 1; m < 16; m <<= 1)
#pragma unroll
        for (int s = 0; s < 8; ++s) {
            unsigned o1 = (unsigned)__shfl_xor((int)p1[s], m, 64);
            unsigned o2 = (unsigned)__shfl_xor((int)p2[s], m, 64);
            unsigned lo = p1[s] < o1 ? p1[s] : o1;
            unsigned hi = p1[s] < o1 ? o1 : p1[s];
            unsigned n2 = p2[s] < o2 ? p2[s] : o2;
            p2[s] = hi < n2 ? hi : n2;
            p1[s] = lo;
        }

    if (c16 == 0) {
#pragma unroll
        for (int s = 0; s < 8; ++s) {
            int tv = s >> 2, r = s & 3;
            int row = w * 32 + tv * 16 + q * 4 + r;    // block-local
            s_widx[row] = (int)(p1[s] & 1023u);
            if (p2[s] - p1[s] <= MARGIN_P) {
                int pos = atomicAdd((int*)(ws + CNT_OFF), 1);
                if (pos < LIST_CAP) ((int*)(ws + LIST_OFF))[pos] = nb + row;
            }
        }
    }
    __syncthreads();

    // ---- gather-write (stores coalesced across rows)
    {
        int r = t & 127, half = t >> 7;
        int widx = s_widx[r];
        const float4* er = (const float4*)(cb + (size_t)widx * D + half * 32);
        float* op = out + (size_t)b * (D * HW) + hw0 + r + (size_t)(half * 32) * HW;
#pragma unroll
        for (int i = 0; i < 8; ++i) {
            float4 v = er[i];
            op[(size_t)(i * 4 + 0) * HW] = v.x;
            op[(size_t)(i * 4 + 1) * HW] = v.y;
            op[(size_t)(i * 4 + 2) * HW] = v.z;
            op[(size_t)(i * 4 + 3) * HW] = v.w;
        }
    }
}

// --- rescore: exact fp32-emulated chain over all codes for flagged vectors ---
__global__ __launch_bounds__(64) void vq_rescore(const float* __restrict__ in,
                                                 const float* __restrict__ cb,
                                                 float* __restrict__ out,
                                                 char* __restrict__ ws) {
    int count = *(const int*)(ws + CNT_OFF);
    if (count > LIST_CAP) count = LIST_CAP;
    const int* list = (const int*)(ws + LIST_OFF);
    const float* seg = (const float*)(ws + SE_OFF);
    int lane = threadIdx.x;
    for (int i = blockIdx.x; i < count; i += gridDim.x) {
        int n = list[i];
        int b = n >> 12, hw = n & (HW - 1);
        const float* xin = in + (size_t)b * (D * HW) + hw;
        float x[D];
#pragma unroll
        for (int d = 0; d < D; ++d) x[d] = xin[(size_t)d * HW];
        float y[D];
#pragma unroll
        for (int d = 0; d < D; ++d) y[d] = __fadd_rn(x[d], x[d]);
        float sx = np_sumsq64(x);
        float best = 3.4e38f; int bidx = 0;
        for (int c = 0; c < 16; ++c) {
            int k = c * 64 + lane;                      // ascending k per lane
            const float4* e4 = (const float4*)(cb + (size_t)k * D);
            float acc = 0.f;
#pragma unroll
            for (int p = 0; p < 16; ++p) {              // exact sequential chain
                float4 ev = e4[p];
                acc = __fmaf_rn(y[p * 4 + 0], ev.x, acc);
                acc = __fmaf_rn(y[p * 4 + 1], ev.y, acc);
                acc = __fmaf_rn(y[p * 4 + 2], ev.z, acc);
                acc = __fmaf_rn(y[p * 4 + 3], ev.w, acc);
            }
            float dist = __fsub_rn(__fadd_rn(sx, seg[k]), acc);
            if (dist < best) { best = dist; bidx = k; }
        }
#pragma unroll
        for (int m = 1; m < 64; m <<= 1) {              // (val, idx) lex-min
            float ob = __shfl_xor(best, m, 64);
            int oi = __shfl_xor(bidx, m, 64);
            if (ob < best || (ob == best && oi < bidx)) { best = ob; bidx = oi; }
        }
        out[(size_t)b * (D * HW) + (size_t)lane * HW + hw] = cb[(size_t)bidx * D + lane];
    }
}

extern "C" void kernel_launch(void* const* d_in, const int* in_sizes, int n_in,
                              void* d_out, int out_size, void* d_ws, size_t ws_size,
                              hipStream_t stream) {
    const float* in = (const float*)d_in[0];
    const float* cb = (const float*)d_in[1];
    float* out = (float*)d_out;
    char* ws = (char*)d_ws;

    if (ws_size < (size_t)WS_NEED) return;   // fail visibly, never OOB

    prep_cb<<<dim3(K / 256), dim3(256), 0, stream>>>(cb, ws);
    vq_main<<<dim3(NTOTAL / 128), dim3(256), 0, stream>>>(in, cb, out, ws);
    vq_rescore<<<dim3(1024), dim3(64), 0, stream>>>(in, cb, out, ws);
}